// Round 1
// baseline (2068.092 us; speedup 1.0000x reference)
//
#include <hip/hip_runtime.h>

// Sizes (derived at runtime from in_sizes, constants for the fixed dims)
#define F 64      // F_IN == HID
#define EF 32
#define COUT 4

// ---------------------------------------------------------------- kernels

__global__ void k_deg(const int* __restrict__ dst, int* __restrict__ deg, int E) {
    int i = blockIdx.x * blockDim.x + threadIdx.x;
    if (i < E) atomicAdd(&deg[dst[i]], 1);
}

__global__ void k_dinv(const int* __restrict__ deg, float* __restrict__ dinv, int n) {
    int i = blockIdx.x * blockDim.x + threadIdx.x;
    if (i < n) dinv[i] = rsqrtf((float)(deg[i] + 1));  // +1 self-loop; always >=1
}

// M layout: Mz[4096] | Mh[4096] | vz[64] | vh[64]
// Mz[k][j] = sum_i Wz[k,i]*Wlz[i,j]   (Wlz top half),  vz[j] = sum_i bz[i]*Wlz[i,j] + blz[j]
__global__ void k_weights(const float* __restrict__ Wz, const float* __restrict__ bz,
                          const float* __restrict__ Wh, const float* __restrict__ bh,
                          const float* __restrict__ Wlz, const float* __restrict__ blz,
                          const float* __restrict__ Wlh, const float* __restrict__ blh,
                          float* __restrict__ M) {
    int j = threadIdx.x;   // 0..63
    int k = blockIdx.x;    // 0..64 (64 = biases)
    if (k < 64) {
        float sz = 0.f, sh = 0.f;
        for (int i = 0; i < 64; ++i) {
            sz += Wz[k * 64 + i] * Wlz[i * 64 + j];
            sh += Wh[k * 64 + i] * Wlh[i * 64 + j];
        }
        M[k * 64 + j]        = sz;
        M[4096 + k * 64 + j] = sh;
    } else {
        float sz = blz[j], sh = blh[j];
        for (int i = 0; i < 64; ++i) {
            sz += bz[i] * Wlz[i * 64 + j];
            sh += bh[i] * Wlh[i * 64 + j];
        }
        M[8192 + j] = sz;
        M[8256 + j] = sh;
    }
}

// xagg[d] += x[s] * dinv[s]*dinv[d]   (16 threads/edge, float4 each)
__global__ void k_scatter(const int* __restrict__ src, const int* __restrict__ dst,
                          const float* __restrict__ x, const float* __restrict__ dinv,
                          float* __restrict__ xagg, int E) {
    long long gt = (long long)blockIdx.x * blockDim.x + threadIdx.x;
    int e = (int)(gt >> 4);
    if (e >= E) return;
    int f = ((int)gt & 15) * 4;
    int s = src[e], d = dst[e];
    float w = dinv[s] * dinv[d];
    const float4 v = *(const float4*)(x + (size_t)s * F + f);
    float* p = xagg + (size_t)d * F + f;
    atomicAdd(p + 0, v.x * w);
    atomicAdd(p + 1, v.y * w);
    atomicAdd(p + 2, v.z * w);
    atomicAdd(p + 3, v.w * w);
}

// Per node: a = xagg + x*dinv^2 ; Z = sigmoid(a@Mz+vz); T = tanh(a@Mh+vh); h=(1-Z)T
// P = h@W1a + b1 (overwrites xagg buffer) ; Q = h@W1b
// 512 threads = 8 waves, 4 nodes per wave per iteration, grid-stride.
__global__ __launch_bounds__(512) void k_node(
    const float* __restrict__ x, const float* __restrict__ dinv,
    const float* __restrict__ M, const float* __restrict__ W1,
    const float* __restrict__ b1,
    float* __restrict__ P, float* __restrict__ Q, int n) {
    __shared__ float sm[16384];  // Mz | Mh | W1a | W1b  (64 KiB)
    for (int i = threadIdx.x; i < 8192; i += 512) sm[i] = M[i];
    for (int i = threadIdx.x; i < 8192; i += 512) sm[8192 + i] = W1[i];
    __syncthreads();
    int wid = threadIdx.x >> 6, lane = threadIdx.x & 63;
    float vz = M[8192 + lane], vh = M[8256 + lane], b1v = b1[lane];
    int wave = blockIdx.x * 8 + wid;
    int nwaves = gridDim.x * 8;
    for (int base = wave * 4; base < n; base += nwaves * 4) {
        float a[4], gz[4], gh[4];
        #pragma unroll
        for (int i = 0; i < 4; ++i) {
            int node = base + i;
            if (node < n) {
                float di = dinv[node];
                a[i] = P[(size_t)node * F + lane] + x[(size_t)node * F + lane] * di * di;
            } else a[i] = 0.f;
            gz[i] = vz; gh[i] = vh;
        }
        #pragma unroll 8
        for (int k = 0; k < 64; ++k) {
            float mz = sm[k * 64 + lane], mh = sm[4096 + k * 64 + lane];
            #pragma unroll
            for (int i = 0; i < 4; ++i) {
                float ak = __shfl(a[i], k);
                gz[i] += ak * mz;
                gh[i] += ak * mh;
            }
        }
        float h[4], p[4], q[4];
        #pragma unroll
        for (int i = 0; i < 4; ++i) {
            float z = 1.f / (1.f + __expf(-gz[i]));
            float t = tanhf(gh[i]);
            h[i] = (1.f - z) * t;
            p[i] = b1v; q[i] = 0.f;
        }
        #pragma unroll 8
        for (int k = 0; k < 64; ++k) {
            float w1a = sm[8192 + k * 64 + lane], w1b = sm[12288 + k * 64 + lane];
            #pragma unroll
            for (int i = 0; i < 4; ++i) {
                float hk = __shfl(h[i], k);
                p[i] += hk * w1a;
                q[i] += hk * w1b;
            }
        }
        #pragma unroll
        for (int i = 0; i < 4; ++i) {
            int node = base + i;
            if (node < n) {
                P[(size_t)node * F + lane] = p[i];
                Q[(size_t)node * F + lane] = q[i];
            }
        }
    }
}

// One edge per LANE. W1c/W2/b2 addresses are wave-uniform -> scalar loads (SALU pipe).
__global__ __launch_bounds__(256) void k_edge(
    const int* __restrict__ src, const int* __restrict__ dst,
    const float* __restrict__ attr,
    const float* __restrict__ P, const float* __restrict__ Q,
    const float* __restrict__ W1c, const float* __restrict__ W2,
    const float* __restrict__ b2, float* __restrict__ out, int E) {
    int e = blockIdx.x * 256 + threadIdx.x;
    if (e >= E) return;
    int s = src[e], d = dst[e];
    float ar[EF];
    #pragma unroll
    for (int k4 = 0; k4 < EF / 4; ++k4) {
        float4 v = *(const float4*)(attr + (size_t)e * EF + k4 * 4);
        ar[k4 * 4 + 0] = v.x; ar[k4 * 4 + 1] = v.y;
        ar[k4 * 4 + 2] = v.z; ar[k4 * 4 + 3] = v.w;
    }
    const float* Ps = P + (size_t)s * F;
    const float* Qd = Q + (size_t)d * F;
    float o0 = b2[0], o1 = b2[1], o2 = b2[2], o3 = b2[3];
    #pragma unroll 2
    for (int j4 = 0; j4 < 16; ++j4) {
        float4 ps = *(const float4*)(Ps + j4 * 4);
        float4 qd = *(const float4*)(Qd + j4 * 4);
        float pre[4] = {ps.x + qd.x, ps.y + qd.y, ps.z + qd.z, ps.w + qd.w};
        #pragma unroll
        for (int jj = 0; jj < 4; ++jj) {
            int j = j4 * 4 + jj;
            float acc = pre[jj];
            #pragma unroll
            for (int k = 0; k < EF; ++k) acc += ar[k] * W1c[k * 64 + j];
            float h = fmaxf(acc, 0.f);
            o0 += h * W2[j * 4 + 0];
            o1 += h * W2[j * 4 + 1];
            o2 += h * W2[j * 4 + 2];
            o3 += h * W2[j * 4 + 3];
        }
    }
    float4 o = make_float4(o0, o1, o2, o3);
    *(float4*)(out + (size_t)e * 4) = o;
}

// ---------------------------------------------------------------- launch

extern "C" void kernel_launch(void* const* d_in, const int* in_sizes, int n_in,
                              void* d_out, int out_size, void* d_ws, size_t ws_size,
                              hipStream_t stream) {
    const float* x    = (const float*)d_in[0];
    const int*   ei   = (const int*)d_in[1];
    const float* attr = (const float*)d_in[2];
    const float* Wz   = (const float*)d_in[3];
    const float* bz   = (const float*)d_in[4];
    const float* Wh   = (const float*)d_in[7];
    const float* bh   = (const float*)d_in[8];
    const float* Wlz  = (const float*)d_in[9];
    const float* blz  = (const float*)d_in[10];
    const float* Wlh  = (const float*)d_in[13];
    const float* blh  = (const float*)d_in[14];
    const float* W1   = (const float*)d_in[15];
    const float* b1   = (const float*)d_in[16];
    const float* W2   = (const float*)d_in[17];
    const float* b2   = (const float*)d_in[18];
    float* out = (float*)d_out;

    const int N = in_sizes[0] / F;
    const int E = in_sizes[1] / 2;
    const int* src = ei;
    const int* dst = ei + E;

    // workspace layout (floats)
    float* w    = (float*)d_ws;
    float* P    = w;                              // N*64  (xagg, then P in place)
    float* Q    = w + (size_t)N * F;              // N*64
    int*   deg  = (int*)(w + 2 * (size_t)N * F);  // N ints
    float* dinv = w + 2 * (size_t)N * F + N;      // N
    float* M    = dinv + N;                       // 8320

    hipMemsetAsync(P, 0, (size_t)N * F * sizeof(float), stream);   // xagg accumulator
    hipMemsetAsync(deg, 0, (size_t)N * sizeof(int), stream);

    k_deg<<<(E + 255) / 256, 256, 0, stream>>>(dst, deg, E);
    k_dinv<<<(N + 255) / 256, 256, 0, stream>>>(deg, dinv, N);
    k_weights<<<65, 64, 0, stream>>>(Wz, bz, Wh, bh, Wlz, blz, Wlh, blh, M);

    long long sc_threads = (long long)E * 16;
    int sc_blocks = (int)((sc_threads + 255) / 256);
    k_scatter<<<sc_blocks, 256, 0, stream>>>(src, dst, x, dinv, P, E);

    k_node<<<400, 512, 0, stream>>>(x, dinv, M, W1, b1, P, Q, N);

    const float* W1c = W1 + 128 * 64;
    k_edge<<<(E + 255) / 256, 256, 0, stream>>>(src, dst, attr, P, Q, W1c, W2, b2, out, E);
}

// Round 2
// 907.472 us; speedup vs baseline: 2.2790x; 2.2790x over previous
//
#include <hip/hip_runtime.h>

#define F 64      // F_IN == HID
#define EF 32
#define COUT 4

// ---------------------------------------------------------------- kernels

__global__ void k_deg(const int* __restrict__ dst, int* __restrict__ deg, int E) {
    int i = blockIdx.x * blockDim.x + threadIdx.x;
    if (i < E) atomicAdd(&deg[dst[i]], 1);
}

__global__ void k_dinv(const int* __restrict__ deg, float* __restrict__ dinv, int n) {
    int i = blockIdx.x * blockDim.x + threadIdx.x;
    if (i < n) dinv[i] = rsqrtf((float)(deg[i] + 1));  // +1 self-loop; always >=1
}

// ---- exclusive scan of deg -> rowptr (3 kernels) ----

__global__ void k_blocksum(const int* __restrict__ deg, int* __restrict__ bsum, int n) {
    __shared__ int sm[256];
    int i = blockIdx.x * 256 + threadIdx.x;
    sm[threadIdx.x] = (i < n) ? deg[i] : 0;
    __syncthreads();
    for (int s = 128; s > 0; s >>= 1) {
        if (threadIdx.x < s) sm[threadIdx.x] += sm[threadIdx.x + s];
        __syncthreads();
    }
    if (threadIdx.x == 0) bsum[blockIdx.x] = sm[0];
}

// single wave; exclusive scan of nb block sums
__global__ void k_scanb(const int* __restrict__ bsum, int* __restrict__ boffs, int nb) {
    int lane = threadIdx.x;  // 0..63
    int carry = 0;
    for (int base = 0; base < nb; base += 64) {
        int v = (base + lane < nb) ? bsum[base + lane] : 0;
        int incl = v;
        #pragma unroll
        for (int off = 1; off < 64; off <<= 1) {
            int t = __shfl_up(incl, off);
            if (lane >= off) incl += t;
        }
        if (base + lane < nb) boffs[base + lane] = carry + incl - v;
        carry += __shfl(incl, 63);
    }
}

__global__ void k_rowptr(const int* __restrict__ deg, const int* __restrict__ boffs,
                         int* __restrict__ rowptr, int n) {
    __shared__ int sm[256];
    int tid = threadIdx.x;
    int i = blockIdx.x * 256 + tid;
    int v = (i < n) ? deg[i] : 0;
    sm[tid] = v;
    __syncthreads();
    for (int off = 1; off < 256; off <<= 1) {
        int t = (tid >= off) ? sm[tid - off] : 0;
        __syncthreads();
        sm[tid] += t;
        __syncthreads();
    }
    if (i < n) rowptr[i] = boffs[blockIdx.x] + sm[tid] - v;
}

// scatter edge src indices into CSR buckets (int atomics only)
__global__ void k_bucket(const int* __restrict__ src, const int* __restrict__ dst,
                         const int* __restrict__ rowptr, int* __restrict__ fill,
                         int* __restrict__ es, int E) {
    int e = blockIdx.x * 256 + threadIdx.x;
    if (e >= E) return;
    int d = dst[e];
    int pos = rowptr[d] + atomicAdd(&fill[d], 1);
    es[pos] = src[e];
}

// gather-aggregate: one wave per node, lane = feature
__global__ __launch_bounds__(256) void k_agg(
    const float* __restrict__ x, const float* __restrict__ dinv,
    const int* __restrict__ es, const int* __restrict__ rowptr,
    const int* __restrict__ deg, float* __restrict__ xagg, int n) {
    int node = (blockIdx.x * 256 + threadIdx.x) >> 6;
    int lane = threadIdx.x & 63;
    if (node >= n) return;
    int start = rowptr[node], cnt = deg[node];
    float di = dinv[node];
    float acc = x[(size_t)node * F + lane] * di * di;  // self-loop term
    for (int base = 0; base < cnt; base += 64) {
        int m = min(64, cnt - base);
        int s = 0; float dv = 0.f;
        if (lane < m) { s = es[start + base + lane]; dv = dinv[s]; }
        for (int i = 0; i < m; ++i) {
            int si = __shfl(s, i);
            float wv = __shfl(dv, i) * di;
            acc += x[(size_t)si * F + lane] * wv;
        }
    }
    xagg[(size_t)node * F + lane] = acc;
}

// M layout: Mz[4096] | Mh[4096] | vz[64] | vh[64]
__global__ void k_weights(const float* __restrict__ Wz, const float* __restrict__ bz,
                          const float* __restrict__ Wh, const float* __restrict__ bh,
                          const float* __restrict__ Wlz, const float* __restrict__ blz,
                          const float* __restrict__ Wlh, const float* __restrict__ blh,
                          float* __restrict__ M) {
    int j = threadIdx.x;   // 0..63
    int k = blockIdx.x;    // 0..64 (64 = biases)
    if (k < 64) {
        float sz = 0.f, sh = 0.f;
        for (int i = 0; i < 64; ++i) {
            sz += Wz[k * 64 + i] * Wlz[i * 64 + j];
            sh += Wh[k * 64 + i] * Wlh[i * 64 + j];
        }
        M[k * 64 + j]        = sz;
        M[4096 + k * 64 + j] = sh;
    } else {
        float sz = blz[j], sh = blh[j];
        for (int i = 0; i < 64; ++i) {
            sz += bz[i] * Wlz[i * 64 + j];
            sh += bh[i] * Wlh[i * 64 + j];
        }
        M[8192 + j] = sz;
        M[8256 + j] = sh;
    }
}

// Per node: a = xagg ; Z = sigmoid(a@Mz+vz); T = tanh(a@Mh+vh); h=(1-Z)T
// P = h@W1a + b1 ; Q = h@W1b
__global__ __launch_bounds__(512) void k_node(
    const float* __restrict__ xagg, const float* __restrict__ M,
    const float* __restrict__ W1, const float* __restrict__ b1,
    float* __restrict__ P, float* __restrict__ Q, int n) {
    __shared__ float sm[16384];  // Mz | Mh | W1a | W1b  (64 KiB)
    for (int i = threadIdx.x; i < 8192; i += 512) sm[i] = M[i];
    for (int i = threadIdx.x; i < 8192; i += 512) sm[8192 + i] = W1[i];
    __syncthreads();
    int wid = threadIdx.x >> 6, lane = threadIdx.x & 63;
    float vz = M[8192 + lane], vh = M[8256 + lane], b1v = b1[lane];
    int wave = blockIdx.x * 8 + wid;
    int nwaves = gridDim.x * 8;
    for (int base = wave * 4; base < n; base += nwaves * 4) {
        float a[4], gz[4], gh[4];
        #pragma unroll
        for (int i = 0; i < 4; ++i) {
            int node = base + i;
            a[i] = (node < n) ? xagg[(size_t)node * F + lane] : 0.f;
            gz[i] = vz; gh[i] = vh;
        }
        #pragma unroll 8
        for (int k = 0; k < 64; ++k) {
            float mz = sm[k * 64 + lane], mh = sm[4096 + k * 64 + lane];
            #pragma unroll
            for (int i = 0; i < 4; ++i) {
                float ak = __shfl(a[i], k);
                gz[i] += ak * mz;
                gh[i] += ak * mh;
            }
        }
        float h[4], p[4], q[4];
        #pragma unroll
        for (int i = 0; i < 4; ++i) {
            float z = 1.f / (1.f + __expf(-gz[i]));
            float t = tanhf(gh[i]);
            h[i] = (1.f - z) * t;
            p[i] = b1v; q[i] = 0.f;
        }
        #pragma unroll 8
        for (int k = 0; k < 64; ++k) {
            float w1a = sm[8192 + k * 64 + lane], w1b = sm[12288 + k * 64 + lane];
            #pragma unroll
            for (int i = 0; i < 4; ++i) {
                float hk = __shfl(h[i], k);
                p[i] += hk * w1a;
                q[i] += hk * w1b;
            }
        }
        #pragma unroll
        for (int i = 0; i < 4; ++i) {
            int node = base + i;
            if (node < n) {
                P[(size_t)node * F + lane] = p[i];
                Q[(size_t)node * F + lane] = q[i];
            }
        }
    }
}

// One edge per LANE. W1c/W2/b2 addresses are wave-uniform -> scalar loads.
__global__ __launch_bounds__(256) void k_edge(
    const int* __restrict__ src, const int* __restrict__ dst,
    const float* __restrict__ attr,
    const float* __restrict__ P, const float* __restrict__ Q,
    const float* __restrict__ W1c, const float* __restrict__ W2,
    const float* __restrict__ b2, float* __restrict__ out, int E) {
    int e = blockIdx.x * 256 + threadIdx.x;
    if (e >= E) return;
    int s = src[e], d = dst[e];
    float ar[EF];
    #pragma unroll
    for (int k4 = 0; k4 < EF / 4; ++k4) {
        float4 v = *(const float4*)(attr + (size_t)e * EF + k4 * 4);
        ar[k4 * 4 + 0] = v.x; ar[k4 * 4 + 1] = v.y;
        ar[k4 * 4 + 2] = v.z; ar[k4 * 4 + 3] = v.w;
    }
    const float* Ps = P + (size_t)s * F;
    const float* Qd = Q + (size_t)d * F;
    float o0 = b2[0], o1 = b2[1], o2 = b2[2], o3 = b2[3];
    #pragma unroll 2
    for (int j4 = 0; j4 < 16; ++j4) {
        float4 ps = *(const float4*)(Ps + j4 * 4);
        float4 qd = *(const float4*)(Qd + j4 * 4);
        float pre[4] = {ps.x + qd.x, ps.y + qd.y, ps.z + qd.z, ps.w + qd.w};
        #pragma unroll
        for (int jj = 0; jj < 4; ++jj) {
            int j = j4 * 4 + jj;
            float acc = pre[jj];
            #pragma unroll
            for (int k = 0; k < EF; ++k) acc += ar[k] * W1c[k * 64 + j];
            float h = fmaxf(acc, 0.f);
            o0 += h * W2[j * 4 + 0];
            o1 += h * W2[j * 4 + 1];
            o2 += h * W2[j * 4 + 2];
            o3 += h * W2[j * 4 + 3];
        }
    }
    float4 o = make_float4(o0, o1, o2, o3);
    *(float4*)(out + (size_t)e * 4) = o;
}

// ---------------------------------------------------------------- launch

extern "C" void kernel_launch(void* const* d_in, const int* in_sizes, int n_in,
                              void* d_out, int out_size, void* d_ws, size_t ws_size,
                              hipStream_t stream) {
    const float* x    = (const float*)d_in[0];
    const int*   ei   = (const int*)d_in[1];
    const float* attr = (const float*)d_in[2];
    const float* Wz   = (const float*)d_in[3];
    const float* bz   = (const float*)d_in[4];
    const float* Wh   = (const float*)d_in[7];
    const float* bh   = (const float*)d_in[8];
    const float* Wlz  = (const float*)d_in[9];
    const float* blz  = (const float*)d_in[10];
    const float* Wlh  = (const float*)d_in[13];
    const float* blh  = (const float*)d_in[14];
    const float* W1   = (const float*)d_in[15];
    const float* b1   = (const float*)d_in[16];
    const float* W2   = (const float*)d_in[17];
    const float* b2   = (const float*)d_in[18];
    float* out = (float*)d_out;

    const int N = in_sizes[0] / F;
    const int E = in_sizes[1] / 2;
    const int* src = ei;
    const int* dst = ei + E;
    const int NB = (N + 255) / 256;

    // workspace layout (4-byte units)
    float* w     = (float*)d_ws;
    float* P     = w;                       // N*64 (xagg, then P in place)
    float* Q     = P + (size_t)N * F;       // N*64
    int*   deg   = (int*)(Q + (size_t)N * F);  // N
    float* dinv  = (float*)(deg + N);       // N
    float* M     = dinv + N;                // 8320
    int*   rowptr= (int*)(M + 8320);        // N
    int*   fill  = rowptr + N;              // N
    int*   bsum  = fill + N;                // NB (<=512)
    int*   boffs = bsum + 512;              // NB
    int*   es    = boffs + 512;             // E

    hipMemsetAsync(deg, 0, (size_t)N * sizeof(int), stream);
    hipMemsetAsync(fill, 0, (size_t)N * sizeof(int), stream);

    k_deg<<<(E + 255) / 256, 256, 0, stream>>>(dst, deg, E);
    k_dinv<<<NB, 256, 0, stream>>>(deg, dinv, N);
    k_weights<<<65, 64, 0, stream>>>(Wz, bz, Wh, bh, Wlz, blz, Wlh, blh, M);

    // CSR build
    k_blocksum<<<NB, 256, 0, stream>>>(deg, bsum, N);
    k_scanb<<<1, 64, 0, stream>>>(bsum, boffs, NB);
    k_rowptr<<<NB, 256, 0, stream>>>(deg, boffs, rowptr, N);
    k_bucket<<<(E + 255) / 256, 256, 0, stream>>>(src, dst, rowptr, fill, es, E);

    // gather aggregation (wave per node)
    k_agg<<<(N * 64 + 255) / 256, 256, 0, stream>>>(x, dinv, es, rowptr, deg, P, N);

    k_node<<<400, 512, 0, stream>>>(P, M, W1, b1, P, Q, N);

    const float* W1c = W1 + 128 * 64;
    k_edge<<<(E + 255) / 256, 256, 0, stream>>>(src, dst, attr, P, Q, W1c, W2, b2, out, E);
}